// Round 18
// baseline (774.918 us; speedup 1.0000x reference)
//
#include <hip/hip_runtime.h>
#include <cstdint>
#include <cstddef>

#define P_TOT 114688   // N*H*W = 4*128*224
#define W_IMG 224
#define H_IMG 128
#define WP 228         // padded row width (1 left, 3 right)
#define HP 130         // padded rows (1 top, 1 bottom)

typedef _Float16 f16;
typedef __attribute__((ext_vector_type(8))) _Float16 f16x8;
typedef __attribute__((ext_vector_type(4))) _Float16 f16x4;
typedef __attribute__((ext_vector_type(4))) float f32x4;
typedef __attribute__((ext_vector_type(4))) float float4v;

#define WAITVM(N) asm volatile("s_waitcnt vmcnt(" #N ")" ::: "memory")
#define SGB(mask, n) __builtin_amdgcn_sched_group_barrier(mask, n, 0)

__device__ __forceinline__ void barrier_sync() {
  asm volatile("" ::: "memory");
  __builtin_amdgcn_s_barrier();
  asm volatile("" ::: "memory");
}

__device__ __forceinline__ void gload16(const void* g, void* l) {
  __builtin_amdgcn_global_load_lds((const __attribute__((address_space(1))) void*)g,
                                   (__attribute__((address_space(3))) void*)l, 16, 0, 0);
}

__device__ __forceinline__ size_t pad_px(int n, int h, int w) {
  return ((size_t)(n * HP + h + 1)) * WP + (w + 1);
}

// ---------------- halo zeroing helper (fused into producers) --------------------
__device__ __forceinline__ void halo_zero(f16* __restrict__ slab, int CS, int hidx) {
  int c8n = CS >> 3;
  int c8 = hidx % c8n;
  int rest = hidx / c8n;
  if (rest >= 4 * 968) return;
  int n = rest / 968, i = rest % 968;
  int h, w;
  if (i < 456) { h = (i < 228) ? 0 : 129; w = i % 228; }
  else { int j = i - 456; h = 1 + (j >> 2); int k = j & 3; w = (k == 0) ? 0 : (224 + k); }
  size_t pp = ((size_t)(n * HP + h)) * WP + w;
  *(f16x8*)(slab + pp * CS + c8 * 8) = (f16x8){0, 0, 0, 0, 0, 0, 0, 0};
}

// ---- pack input (fp32 NCHW -> f16 padded-NHWC, swizzled), float4-coalesced -----
__global__ void k_pack_x(const float* __restrict__ x, f16* __restrict__ xb) {
  constexpr int MAIN = P_TOT / 32;
  if (blockIdx.x >= MAIN) {
    halo_zero(xb, 256, (blockIdx.x - MAIN) * 256 + threadIdx.x);
    return;
  }
  int tid = threadIdx.x;
  int pg  = tid & 7;                  // 0..7  (4-px group)
  int c8  = tid >> 3;                 // 0..31
  int p0  = blockIdx.x * 32 + pg * 4; // linear pixel in [0, P_TOT)
  int n   = p0 / (H_IMG * W_IMG);
  int pim = p0 % (H_IMG * W_IMG);     // linear within image plane; +3 stays in plane
  const float* src = x + ((size_t)(n * 256 + c8 * 8)) * (H_IMG * W_IMG) + pim;
  float4v v[8];
#pragma unroll
  for (int j = 0; j < 8; j++) v[j] = *(const float4v*)(src + (size_t)j * (H_IMG * W_IMG));
#pragma unroll
  for (int k = 0; k < 4; k++) {
    int p = pim + k;
    int w = p % W_IMG;
    int h = p / W_IMG;
    f16x8 o;
#pragma unroll
    for (int j = 0; j < 8; j++) o[j] = (f16)v[j][k];
    int c8s = (c8 & ~3) | ((c8 ^ (w >> 1)) & 3);
    *(f16x8*)(xb + pad_px(n, h, w) * 256 + c8s * 8) = o;
  }
}

// ---- pack weights into [q'][OT][32], q' = (kt*CC + c)*3 + d, kk = kt*3 + d -----
__device__ __forceinline__ void pack_w_one(const float* __restrict__ wa,
                                           const float* __restrict__ wb,
                                           f16* __restrict__ dst, int mode, int OT,
                                           int CS, int Coh, int Cih, int gid) {
  int j  = gid & 31;
  int t1 = gid >> 5;
  int o  = t1 % OT;
  int t2 = t1 / OT;                   // q'
  int CCc = CS >> 5;
  int d  = t2 % 3;
  int u  = t2 / 3;
  int cc = u % CCc;
  int kt = u / CCc;
  int kk = kt * 3 + d;
  int chunkT = ((j >> 3) ^ (o >> 1)) & 3;
  int is = cc * 32 + chunkT * 8 + (j & 7);
  float val = 0.f;
  if (mode == 0) {
    val = (o < Coh) ? wa[((size_t)o * Cih + is) * 9 + kk]
                    : wb[((size_t)(o - Coh) * Cih + is) * 9 + kk];
  } else if (mode == 1) {
    if (o < Coh) {
      val = (is < Cih) ? wa[((size_t)o * Cih + is) * 9 + kk]
                       : -wb[((size_t)o * Cih + (is - Cih)) * 9 + kk];
    } else {
      int oo = o - Coh;
      val = (is < Cih) ? wb[((size_t)oo * Cih + is) * 9 + kk]
                       : wa[((size_t)oo * Cih + (is - Cih)) * 9 + kk];
    }
  } else {
    if (o == 0)      val = wa[(size_t)is * 9 + kk];
    else if (o == 1) val = wb[(size_t)is * 9 + kk];
    else if (o == 2) val = wb[(size_t)(96 + is) * 9 + kk];
  }
  dst[gid] = (f16)val;
}

// all 5 weight packs in one launch; sizes: 663552, 497664, 331776, 331776, 13824
__global__ void k_pack_w_all(const float* w1r, const float* w1i,
                             const float* w2r, const float* w2i,
                             const float* w3r, const float* w3i,
                             const float* w4r, const float* w4i,
                             const float* wc,  const float* wg,
                             f16* A1, f16* A2, f16* A3, f16* A4, f16* AH) {
  int gid = blockIdx.x * 256 + threadIdx.x;
  if (gid < 663552)        pack_w_one(w1r, w1i, A1, 0, 288, 256, 144, 256, gid);
  else if (gid < 1161216)  pack_w_one(w2r, w2i, A2, 1, 192, 288,  96, 144, gid - 663552);
  else if (gid < 1492992)  pack_w_one(w3r, w3i, A3, 1, 192, 192,  96,  96, gid - 1161216);
  else if (gid < 1824768)  pack_w_one(w4r, w4i, A4, 1, 192, 192,  96,  96, gid - 1492992);
  else                     pack_w_one(wc,  wg,  AH, 2,  16,  96,   0,  96, gid - 1824768);
}

// -------- implicit-GEMM conv: triple-staged, fine DS/MFMA interleave ------------
template<int BM, int OT, int CS, int WM, int WN, bool HEAD>
__launch_bounds__(WM * WN * 64)
__global__ void k_gemm(const f16* __restrict__ xb, const f16* __restrict__ Apack,
                       f16* __restrict__ y, float* __restrict__ outh,
                       const float* __restrict__ bcp, const float* __restrict__ bgp,
                       float* __restrict__ sums, float* __restrict__ sumsq) {
  constexpr int NT = WM * WN * 64;
  constexpr int NWV = NT / 64;
  constexpr int CC = CS / 32;
  constexpr int MF = BM / (WM * 16);       // 3 (head: 1)
  constexpr int NF = 224 / (WN * 16);      // 7
  constexpr int NCH = 9 * CC;              // total K chunks of 32
  constexpr int NTR = 3 * CC;              // triples (one per source row x chunk)
  constexpr int A1 = BM / 16;              // A 1KB-chunks per sub-kk (6)
  constexpr int ACHT = 3 * A1;             // A chunks per triple (18)
  constexpr int BCHT = 15;                 // B chunks: 240-px window from w=-1
  constexpr int TCHT = ACHT + BCHT;        // 33
  constexpr int LDS_BYTES = HEAD ? (2 * 15 * 1024) : (2 * TCHT * 1024);
  __shared__ __align__(16) char lds[LDS_BYTES];

  constexpr int NOT = OT / BM;
  constexpr int nwg = NOT * 512;
  int bid = blockIdx.x;
  int swz = (bid & 7) * (nwg >> 3) + (bid >> 3);  // XCD swizzle (nwg % 8 == 0)
  const int ot = swz % NOT;                        // ot fastest -> same-B blocks adjacent
  const int rq = swz / NOT;
  const int n = rq >> 7;
  const int h = rq & 127;
  const int tid  = threadIdx.x;
  const int lane = tid & 63;
  const int wv   = tid >> 6;
  const int wm   = wv % WM;
  const int wn   = wv / WM;
  const int obase  = wm * (MF * 16);
  const int wnbase = wn * (NF * 16);
  const int l15 = lane & 15;
  const int lhi = lane >> 4;
  // A frag: row stride 64B; slot = lhi ^ ((row>>1)&3) -> <=2-way bank aliasing (free)
  const int aoff = l15 * 64 + (((lhi ^ (l15 >> 1)) & 3) << 4);

  f32x4 acc[MF][NF];
#pragma unroll
  for (int mi = 0; mi < MF; mi++)
#pragma unroll
    for (int ni = 0; ni < NF; ni++) acc[mi][ni] = (f32x4){0.f, 0.f, 0.f, 0.f};

  // hoisted per-thread staging bases (branch-free: halo pre-zeroed)
  const char* abase = (const char*)Apack + (size_t)ot * BM * 64 + lane * 16;
  const char* bbase = (const char*)xb +
      (pad_px(n, h, 0) + (lane >> 2)) * (size_t)(CS * 2) + (lane & 3) * 16;

  if constexpr (!HEAD) {
    static_assert(MF == 3 && NF == 7, "interleave schedule assumes 3x7 fragments");
    // per triple jj = kt*CC + c: stage A(3 sub-kk, 18KB) + B row window (15KB),
    // then 3 d-taps, each with fine-grained {1 ds_read : 3 MFMA} interleave.
    auto stage_triple = [&](char* base, int jj) {
      const int kt = jj / CC, c = jj % CC;
      const char* asrcj = abase + (size_t)(jj * 3) * (OT * 64);
      const char* bsrcj = bbase + ((ptrdiff_t)(kt - 1) * WP - 1) * (CS * 2) + c * 64;
#pragma unroll
      for (int i = 0; i < (TCHT + NWV - 1) / NWV; i++) {
        int ck = wv + i * NWV;
        if (ck < TCHT) {
          char* dst = base + ck * 1024;      // wave-uniform
          const char* src;
          if (ck < ACHT) {
            int d = (ck >= 2 * A1) ? 2 : ((ck >= A1) ? 1 : 0);
            src = asrcj + (size_t)d * (OT * 64) + (size_t)(ck - d * A1) * 1024;
          } else {
            src = bsrcj + (size_t)(ck - ACHT) * (16 * CS * 2);
          }
          gload16(src, dst);
        }
      }
    };
    auto compute_d = [&](const char* base, int d) {
      const char* Ab = base + d * (BM * 64);
      const char* Bb = base + ACHT * 1024;
      auto bload = [&](int ni) -> f16x8 {
        int wp = wnbase + ni * 16 + l15 + d - 1;
        int sw = ((lhi ^ (wp >> 1)) & 3) << 4;
        return *(const f16x8*)(Bb + (wp + 1) * 64 + sw);
      };
      f16x8 af0 = *(const f16x8*)(Ab + (obase +  0) * 64 + aoff);
      f16x8 af1 = *(const f16x8*)(Ab + (obase + 16) * 64 + aoff);
      f16x8 af2 = *(const f16x8*)(Ab + (obase + 32) * 64 + aoff);
      f16x8 bA = bload(0);
      f16x8 bB = bload(1);
      __builtin_amdgcn_s_setprio(1);
      SGB(0x100, 5);                                   // 5 leading ds_reads
#define MMA3(bf, col) \
      acc[0][col] = __builtin_amdgcn_mfma_f32_16x16x32_f16(af0, bf, acc[0][col], 0, 0, 0); \
      acc[1][col] = __builtin_amdgcn_mfma_f32_16x16x32_f16(af1, bf, acc[1][col], 0, 0, 0); \
      acc[2][col] = __builtin_amdgcn_mfma_f32_16x16x32_f16(af2, bf, acc[2][col], 0, 0, 0)
      MMA3(bA, 0);  bA = bload(2);  SGB(0x8, 3); SGB(0x100, 1);
      MMA3(bB, 1);  bB = bload(3);  SGB(0x8, 3); SGB(0x100, 1);
      MMA3(bA, 2);  bA = bload(4);  SGB(0x8, 3); SGB(0x100, 1);
      MMA3(bB, 3);  bB = bload(5);  SGB(0x8, 3); SGB(0x100, 1);
      MMA3(bA, 4);  bA = bload(6);  SGB(0x8, 3); SGB(0x100, 1);
      MMA3(bB, 5);
      MMA3(bA, 6);  SGB(0x8, 6);
#undef MMA3
      __builtin_amdgcn_s_setprio(0);
    };
    char* b0 = lds;
    char* b1 = lds + TCHT * 1024;
    stage_triple(b0, 0);
    for (int jj = 0; jj < NTR; ++jj) {
      if (jj + 1 < NTR) {
        stage_triple((jj & 1) ? b0 : b1, jj + 1);
        if (wv == 0) { WAITVM(9); } else { WAITVM(8); }   // own stage(jj) retired
      } else {
        WAITVM(0);
      }
      barrier_sync();
      const char* b = (jj & 1) ? b1 : b0;
      compute_d(b, 0);
      compute_d(b, 1);
      compute_d(b, 2);
      barrier_sync();
    }
  } else {
    // ---- block-shared double buffer + __syncthreads (proven); q' decode ----
    constexpr int HTCH = 1 + 14;            // A 1KB + B 14KB per buffer
    auto stage_blk = [&](char* base, int t) {
      const int d = t % 3, u = t / 3;
      const int c = u % CC, kt = u / CC;
      const int doff = (kt - 1) * WP + (d - 1);
      const char* asrc = abase + (size_t)t * (OT * 64);
      const char* bsrc = bbase + (ptrdiff_t)doff * (CS * 2) + c * 64;
      for (int ck = wv; ck < HTCH; ck += NWV) {
        char* dst = base + ck * 1024;
        if (ck < 1) gload16(asrc, dst);
        else        gload16(bsrc + (size_t)(ck - 1) * (16 * CS * 2), dst);
      }
    };
    auto mfma_one = [&](const f16x8& a, const f16x8& b, f32x4& c) {
      c = __builtin_amdgcn_mfma_f32_16x16x32_f16(a, b, c, 0, 0, 0);
    };
    auto read_frags_blk = [&](const char* base, int t, f16x8* af, f16x8* bfr) {
      const int dw = (t % 3) - 1;
      af[0] = *(const f16x8*)(base + aoff);          // aoff already includes l15*64
#pragma unroll
      for (int ni = 0; ni < NF; ni++) {
        int px = wnbase + ni * 16 + l15;
        int sw = ((lhi ^ ((px + dw) >> 1)) & 3) << 4;
        bfr[ni] = *(const f16x8*)(base + 1024 + px * 64 + sw);
      }
    };
    f16x8 af[MF], bfr[NF];
    stage_blk(lds, 0);
    __syncthreads();
    int buf = 0;
    for (int t = 0; t < NCH; ++t) {
      if (t + 1 < NCH) stage_blk(lds + (buf ^ 1) * 15360, t + 1);
      read_frags_blk(lds + buf * 15360, t, af, bfr);
#pragma unroll
      for (int mi = 0; mi < MF; mi++)
#pragma unroll
        for (int ni = 0; ni < NF; ni++)
          mfma_one(af[mi], bfr[ni], acc[mi][ni]);
      __syncthreads();
      buf ^= 1;
    }
  }

  const size_t prow = pad_px(n, h, 0);
  if constexpr (!HEAD) {
    // store fp16 padded-NHWC output
#pragma unroll
    for (int mi = 0; mi < MF; mi++) {
#pragma unroll
      for (int ni = 0; ni < NF; ni++) {
        int o = obase + mi * 16 + lhi * 4;
        int w = wnbase + ni * 16 + l15;
        f16x4 v4;
#pragma unroll
        for (int j = 0; j < 4; j++) v4[j] = (f16)acc[mi][ni][j];
        *(f16x4*)(y + (prow + w) * OT + ot * BM + o) = v4;
      }
    }
    // fused BN stats: per-channel sum / sumsq partials
    float sv[MF][4], qv[MF][4];
#pragma unroll
    for (int mi = 0; mi < MF; mi++)
#pragma unroll
      for (int j = 0; j < 4; j++) {
        float s = 0.f, q = 0.f;
#pragma unroll
        for (int ni = 0; ni < NF; ni++) {
          float v = acc[mi][ni][j];
          s += v; q += v * v;
        }
        sv[mi][j] = s; qv[mi][j] = q;
      }
#pragma unroll
    for (int m = 1; m < 16; m <<= 1) {
#pragma unroll
      for (int mi = 0; mi < MF; mi++)
#pragma unroll
        for (int j = 0; j < 4; j++) {
          sv[mi][j] += __shfl_xor(sv[mi][j], m);
          qv[mi][j] += __shfl_xor(qv[mi][j], m);
        }
    }
    if (l15 == 0) {
#pragma unroll
      for (int mi = 0; mi < MF; mi++)
#pragma unroll
        for (int j = 0; j < 4; j++) {
          int ch = ot * BM + obase + mi * 16 + lhi * 4 + j;
          atomicAdd(&sums[ch], sv[mi][j]);
          atomicAdd(&sumsq[ch], qv[mi][j]);
        }
    }
  } else {
    if (lhi == 0) {
      float b0 = bcp[0], b1 = bgp[0], b2 = bgp[1];
#pragma unroll
      for (int ni = 0; ni < NF; ni++) {
        int w = wnbase + ni * 16 + l15;
        float c0 = acc[0][ni][0] + b0;
        c0 = 1.f / (1.f + expf(-c0));
        float c1 = acc[0][ni][1] + b1;
        float c2 = acc[0][ni][2] + b2;
        outh[((size_t)(n * 3 + 0) * H_IMG + h) * W_IMG + w] = c0;
        outh[((size_t)(n * 3 + 1) * H_IMG + h) * W_IMG + w] = c1;
        outh[((size_t)(n * 3 + 2) * H_IMG + h) * W_IMG + w] = c2;
      }
    }
  }
}

// ---------------- BN coefficient recompute (fused into consumers) ---------------
template<int O>
__device__ __forceinline__ void bn_coef(const float* __restrict__ sums,
                                        const float* __restrict__ sumsq,
                                        const float* __restrict__ g,
                                        const float* __restrict__ b,
                                        float* sc, float* sh, int tid, int nt) {
  const float inv = 1.0f / (float)P_TOT;
  for (int t = tid; t < O; t += nt) {
    float mean = sums[t] * inv;
    float var  = fmaxf(sumsq[t] * inv - mean * mean, 0.f);
    int gi = (t < O / 2) ? t : (t - O / 2);
    float s = g[gi] * rsqrtf(var + 1e-5f);
    sc[t] = s;
    sh[t] = b[gi] - mean * s;
  }
}

// ------- in-place BN + ReLU + chunk-swizzle, with fused halo-zero blocks --------
template<int O>
__global__ void k_packip(f16* __restrict__ y,
                         const float* __restrict__ sums, const float* __restrict__ sumsq,
                         const float* __restrict__ g, const float* __restrict__ b) {
  constexpr int G32 = O / 32;
  constexpr int MAIN = P_TOT * G32 / 256;
  if (blockIdx.x >= MAIN) {
    halo_zero(y, O, (blockIdx.x - MAIN) * 256 + threadIdx.x);
    return;
  }
  __shared__ float sc[O], sh[O];
  bn_coef<O>(sums, sumsq, g, b, sc, sh, threadIdx.x, 256);
  __syncthreads();
  int gid = blockIdx.x * 256 + threadIdx.x;
  int gg = gid % G32;
  int p = gid / G32;
  int w = p % W_IMG;
  int hh = (p / W_IMG) % H_IMG;
  int nn = p / (W_IMG * H_IMG);
  f16* base = y + pad_px(nn, hh, w) * O + gg * 32;
  f16x8 in[4];
#pragma unroll
  for (int ch = 0; ch < 4; ch++) in[ch] = *(const f16x8*)(base + ch * 8);
  int sw = (w >> 1) & 3;
  f16x8 outv[4];
#pragma unroll
  for (int ch = 0; ch < 4; ch++) {
#pragma unroll
    for (int j = 0; j < 8; j++) {
      int cdx = gg * 32 + ch * 8 + j;
      float f = fmaxf(fmaf((float)in[ch][j], sc[cdx], sh[cdx]), 0.f);
      outv[ch][j] = (f16)f;
    }
  }
#pragma unroll
  for (int ch = 0; ch < 4; ch++) *(f16x8*)(base + ((ch ^ sw) & 3) * 8) = outv[ch];
}

// --- BN(L4) + ReLU + complex magnitude -> 96ch swizzled, + fused halo96(out) ----
__global__ void k_mag(const f16* __restrict__ y,
                      const float* __restrict__ sums, const float* __restrict__ sumsq,
                      const float* __restrict__ g, const float* __restrict__ b,
                      f16* __restrict__ mg) {
  constexpr int MAIN = P_TOT * 12 / 256;
  if (blockIdx.x >= MAIN) {
    halo_zero(mg, 96, (blockIdx.x - MAIN) * 256 + threadIdx.x);
    return;
  }
  __shared__ float sc[192], sh[192];
  bn_coef<192>(sums, sumsq, g, b, sc, sh, threadIdx.x, 256);
  __syncthreads();
  int gid = blockIdx.x * 256 + threadIdx.x;
  int c8 = gid % 12;
  int p  = gid / 12;
  int w  = p % W_IMG;
  int hh = (p / W_IMG) % H_IMG;
  int nn = p / (W_IMG * H_IMG);
  size_t pp = pad_px(nn, hh, w);
  f16x8 r8 = *(const f16x8*)(y + pp * 192 + c8 * 8);
  f16x8 i8 = *(const f16x8*)(y + pp * 192 + 96 + c8 * 8);
  f16x8 outv;
#pragma unroll
  for (int j = 0; j < 8; j++) {
    int cdx = c8 * 8 + j;
    float rr = fmaxf(fmaf((float)r8[j], sc[cdx], sh[cdx]), 0.f);
    float ii = fmaxf(fmaf((float)i8[j], sc[96 + cdx], sh[96 + cdx]), 0.f);
    outv[j] = (f16)sqrtf(rr * rr + ii * ii);
  }
  int c8s = (c8 & ~3) | ((c8 ^ (w >> 1)) & 3);
  *(f16x8*)(mg + pp * 96 + c8s * 8) = outv;
}

// ------------------------------------------------------------------------------
extern "C" void kernel_launch(void* const* d_in, const int* in_sizes, int n_in,
                              void* d_out, int out_size, void* d_ws, size_t ws_size,
                              hipStream_t stream) {
  const float* x   = (const float*)d_in[0];
  const float* w1r = (const float*)d_in[1];
  const float* w1i = (const float*)d_in[2];
  const float* g1  = (const float*)d_in[3];
  const float* b1  = (const float*)d_in[4];
  const float* w2r = (const float*)d_in[5];
  const float* w2i = (const float*)d_in[6];
  const float* g2  = (const float*)d_in[7];
  const float* b2  = (const float*)d_in[8];
  const float* w3r = (const float*)d_in[9];
  const float* w3i = (const float*)d_in[10];
  const float* g3  = (const float*)d_in[11];
  const float* b3  = (const float*)d_in[12];
  const float* w4r = (const float*)d_in[13];
  const float* w4i = (const float*)d_in[14];
  const float* g4  = (const float*)d_in[15];
  const float* b4  = (const float*)d_in[16];
  const float* wc  = (const float*)d_in[17];
  const float* bcp = (const float*)d_in[18];
  const float* wg  = (const float*)d_in[19];
  const float* bgp = (const float*)d_in[20];
  float* out = (float*)d_out;

  char* ws = (char*)d_ws;
  if (ws_size < 137500000ULL) return;

  auto S  = [&](int L) { return (float*)(ws + 16384 + L * 4096); };
  auto Q  = [&](int L) { return (float*)(ws + 16384 + L * 4096) + 512; };
  f16* A1 = (f16*)(ws + 65536);
  f16* A2 = (f16*)(ws + 1392640);
  f16* A3 = (f16*)(ws + 2387968);
  f16* A4 = (f16*)(ws + 3051520);
  f16* AH = (f16*)(ws + 3715072);
  f16* SLA = (f16*)(ws + 4194304);     // padded slab A
  f16* SLB = (f16*)(ws + 65011712);    // padded slab B

  hipMemsetAsync(d_ws, 0, 49152, stream);  // stats sums

  // pack input (+SLA/256 halo); all weight packs in one launch
  k_pack_x<<<P_TOT / 32 + 484, 256, 0, stream>>>(x, SLA);
  k_pack_w_all<<<(1838592) / 256, 256, 0, stream>>>(w1r, w1i, w2r, w2i, w3r, w3i,
                                                    w4r, w4i, wc, wg, A1, A2, A3, A4, AH);

  // L1: 256 -> 288  (read SLA/256, write SLB/288); packip fuses SLB/288 halo
  k_gemm<96, 288, 256, 2, 2, false><<<1536, 256, 0, stream>>>(SLA, A1, SLB, nullptr, nullptr, nullptr, S(0), Q(0));
  k_packip<288><<<P_TOT * 9 / 256 + 545, 256, 0, stream>>>(SLB, S(0), Q(0), g1, b1);

  // L2: 288 -> 192  (read SLB/288, write SLA/192); packip fuses SLA/192 halo
  k_gemm<96, 192, 288, 2, 2, false><<<1024, 256, 0, stream>>>(SLB, A2, SLA, nullptr, nullptr, nullptr, S(1), Q(1));
  k_packip<192><<<P_TOT * 6 / 256 + 363, 256, 0, stream>>>(SLA, S(1), Q(1), g2, b2);

  // L3: 192 -> 192  (read SLA/192, write SLB/192); packip fuses SLB/192 halo
  k_gemm<96, 192, 192, 2, 2, false><<<1024, 256, 0, stream>>>(SLA, A3, SLB, nullptr, nullptr, nullptr, S(2), Q(2));
  k_packip<192><<<P_TOT * 6 / 256 + 363, 256, 0, stream>>>(SLB, S(2), Q(2), g3, b3);

  // L4: 192 -> 192  (read SLB/192, write SLA/192)
  k_gemm<96, 192, 192, 2, 2, false><<<1024, 256, 0, stream>>>(SLB, A4, SLA, nullptr, nullptr, nullptr, S(3), Q(3));

  // BN+ReLU+magnitude -> 96ch head input (read SLA/192, write SLB/96) + SLB/96 halo
  k_mag<<<P_TOT * 12 / 256 + 182, 256, 0, stream>>>(SLA, S(3), Q(3), g4, b4, SLB);

  // head: 96 -> 3 (sigmoid on ch0), writes NCHW fp32 output
  k_gemm<16, 16, 96, 1, 2, true><<<512, 128, 0, stream>>>(SLB, AH, nullptr, out, bcp, bgp, nullptr, nullptr);

  (void)in_sizes; (void)n_in; (void)out_size;
}

// Round 19
// 762.411 us; speedup vs baseline: 1.0164x; 1.0164x over previous
//
#include <hip/hip_runtime.h>
#include <cstdint>
#include <cstddef>

#define P_TOT 114688   // N*H*W = 4*128*224
#define W_IMG 224
#define H_IMG 128
#define WP 228         // padded row width (1 left, 3 right)
#define HP 130         // padded rows (1 top, 1 bottom)

typedef _Float16 f16;
typedef __attribute__((ext_vector_type(8))) _Float16 f16x8;
typedef __attribute__((ext_vector_type(4))) _Float16 f16x4;
typedef __attribute__((ext_vector_type(4))) float f32x4;
typedef __attribute__((ext_vector_type(4))) float float4v;

#define WAITVM(N) asm volatile("s_waitcnt vmcnt(" #N ")" ::: "memory")

__device__ __forceinline__ void barrier_sync() {
  asm volatile("" ::: "memory");
  __builtin_amdgcn_s_barrier();
  asm volatile("" ::: "memory");
}

__device__ __forceinline__ void gload16(const void* g, void* l) {
  __builtin_amdgcn_global_load_lds((const __attribute__((address_space(1))) void*)g,
                                   (__attribute__((address_space(3))) void*)l, 16, 0, 0);
}

__device__ __forceinline__ size_t pad_px(int n, int h, int w) {
  return ((size_t)(n * HP + h + 1)) * WP + (w + 1);
}

// ---------------- halo zeroing helper (fused into producers) --------------------
__device__ __forceinline__ void halo_zero(f16* __restrict__ slab, int CS, int hidx) {
  int c8n = CS >> 3;
  int c8 = hidx % c8n;
  int rest = hidx / c8n;
  if (rest >= 4 * 968) return;
  int n = rest / 968, i = rest % 968;
  int h, w;
  if (i < 456) { h = (i < 228) ? 0 : 129; w = i % 228; }
  else { int j = i - 456; h = 1 + (j >> 2); int k = j & 3; w = (k == 0) ? 0 : (224 + k); }
  size_t pp = ((size_t)(n * HP + h)) * WP + w;
  *(f16x8*)(slab + pp * CS + c8 * 8) = (f16x8){0, 0, 0, 0, 0, 0, 0, 0};
}

// ---- pack input (fp32 NCHW -> f16 padded-NHWC, swizzled), float4-coalesced -----
// main: 256 thr = 8 ch-groups x 32 px (each thread: 4 px x 8 ch via 8 float4 loads)
__global__ void k_pack_x(const float* __restrict__ x, f16* __restrict__ xb) {
  constexpr int MAIN = P_TOT / 32;
  if (blockIdx.x >= MAIN) {
    halo_zero(xb, 256, (blockIdx.x - MAIN) * 256 + threadIdx.x);
    return;
  }
  int tid = threadIdx.x;
  int pg  = tid & 7;                  // 0..7  (4-px group)
  int c8  = tid >> 3;                 // 0..31
  int p0  = blockIdx.x * 32 + pg * 4; // linear pixel in [0, P_TOT)
  int n   = p0 / (H_IMG * W_IMG);
  int pim = p0 % (H_IMG * W_IMG);     // linear within image plane; +3 stays in plane
  const float* src = x + ((size_t)(n * 256 + c8 * 8)) * (H_IMG * W_IMG) + pim;
  float4v v[8];
#pragma unroll
  for (int j = 0; j < 8; j++) v[j] = *(const float4v*)(src + (size_t)j * (H_IMG * W_IMG));
#pragma unroll
  for (int k = 0; k < 4; k++) {
    int p = pim + k;
    int w = p % W_IMG;
    int h = p / W_IMG;
    f16x8 o;
#pragma unroll
    for (int j = 0; j < 8; j++) o[j] = (f16)v[j][k];
    int c8s = (c8 & ~3) | ((c8 ^ (w >> 1)) & 3);
    *(f16x8*)(xb + pad_px(n, h, w) * 256 + c8s * 8) = o;
  }
}

// ---- pack weights into [q'][OT][32], q' = (kt*CC + c)*3 + d, kk = kt*3 + d -----
__device__ __forceinline__ void pack_w_one(const float* __restrict__ wa,
                                           const float* __restrict__ wb,
                                           f16* __restrict__ dst, int mode, int OT,
                                           int CS, int Coh, int Cih, int gid) {
  int j  = gid & 31;
  int t1 = gid >> 5;
  int o  = t1 % OT;
  int t2 = t1 / OT;                   // q'
  int CCc = CS >> 5;
  int d  = t2 % 3;
  int u  = t2 / 3;
  int cc = u % CCc;
  int kt = u / CCc;
  int kk = kt * 3 + d;
  int chunkT = ((j >> 3) ^ (o >> 1)) & 3;
  int is = cc * 32 + chunkT * 8 + (j & 7);
  float val = 0.f;
  if (mode == 0) {
    val = (o < Coh) ? wa[((size_t)o * Cih + is) * 9 + kk]
                    : wb[((size_t)(o - Coh) * Cih + is) * 9 + kk];
  } else if (mode == 1) {
    if (o < Coh) {
      val = (is < Cih) ? wa[((size_t)o * Cih + is) * 9 + kk]
                       : -wb[((size_t)o * Cih + (is - Cih)) * 9 + kk];
    } else {
      int oo = o - Coh;
      val = (is < Cih) ? wb[((size_t)oo * Cih + is) * 9 + kk]
                       : wa[((size_t)oo * Cih + (is - Cih)) * 9 + kk];
    }
  } else {
    if (o == 0)      val = wa[(size_t)is * 9 + kk];
    else if (o == 1) val = wb[(size_t)is * 9 + kk];
    else if (o == 2) val = wb[(size_t)(96 + is) * 9 + kk];
  }
  dst[gid] = (f16)val;
}

// all 5 weight packs in one launch; sizes: 663552, 497664, 331776, 331776, 13824
__global__ void k_pack_w_all(const float* w1r, const float* w1i,
                             const float* w2r, const float* w2i,
                             const float* w3r, const float* w3i,
                             const float* w4r, const float* w4i,
                             const float* wc,  const float* wg,
                             f16* A1, f16* A2, f16* A3, f16* A4, f16* AH) {
  int gid = blockIdx.x * 256 + threadIdx.x;
  if (gid < 663552)        pack_w_one(w1r, w1i, A1, 0, 288, 256, 144, 256, gid);
  else if (gid < 1161216)  pack_w_one(w2r, w2i, A2, 1, 192, 288,  96, 144, gid - 663552);
  else if (gid < 1492992)  pack_w_one(w3r, w3i, A3, 1, 192, 192,  96,  96, gid - 1161216);
  else if (gid < 1824768)  pack_w_one(w4r, w4i, A4, 1, 192, 192,  96,  96, gid - 1492992);
  else                     pack_w_one(wc,  wg,  AH, 2,  16,  96,   0,  96, gid - 1824768);
}

// -------- implicit-GEMM conv: triple-staged (B row shared across dw taps) -------
template<int BM, int OT, int CS, int WM, int WN, bool HEAD>
__launch_bounds__(WM * WN * 64)
__global__ void k_gemm(const f16* __restrict__ xb, const f16* __restrict__ Apack,
                       f16* __restrict__ y, float* __restrict__ outh,
                       const float* __restrict__ bcp, const float* __restrict__ bgp,
                       float* __restrict__ sums, float* __restrict__ sumsq) {
  constexpr int NT = WM * WN * 64;
  constexpr int NWV = NT / 64;
  constexpr int CC = CS / 32;
  constexpr int MF = BM / (WM * 16);       // 3 (head: 1)
  constexpr int NF = 224 / (WN * 16);      // 7
  constexpr int NCH = 9 * CC;              // total K chunks of 32
  constexpr int NTR = 3 * CC;              // triples (one per source row x chunk)
  constexpr int A1 = BM / 16;              // A 1KB-chunks per sub-kk (6)
  constexpr int ACHT = 3 * A1;             // A chunks per triple (18)
  constexpr int BCHT = 15;                 // B chunks: 240-px window from w=-1
  constexpr int TCHT = ACHT + BCHT;        // 33
  constexpr int LDS_BYTES = HEAD ? (2 * 15 * 1024) : (2 * TCHT * 1024);
  __shared__ __align__(16) char lds[LDS_BYTES];

  constexpr int NOT = OT / BM;
  constexpr int nwg = NOT * 512;
  int bid = blockIdx.x;
  int swz = (bid & 7) * (nwg >> 3) + (bid >> 3);  // XCD swizzle (nwg % 8 == 0)
  const int ot = swz % NOT;                        // ot fastest -> same-B blocks adjacent
  const int rq = swz / NOT;
  const int n = rq >> 7;
  const int h = rq & 127;
  const int tid  = threadIdx.x;
  const int lane = tid & 63;
  const int wv   = tid >> 6;
  const int wm   = wv % WM;
  const int wn   = wv / WM;
  const int obase  = wm * (MF * 16);
  const int wnbase = wn * (NF * 16);
  const int l15 = lane & 15;
  const int lhi = lane >> 4;
  // A frag: row stride 64B; slot = lhi ^ ((row>>1)&3) -> <=2-way bank aliasing (free)
  const int aoff = l15 * 64 + (((lhi ^ (l15 >> 1)) & 3) << 4);

  f32x4 acc[MF][NF];
#pragma unroll
  for (int mi = 0; mi < MF; mi++)
#pragma unroll
    for (int ni = 0; ni < NF; ni++) acc[mi][ni] = (f32x4){0.f, 0.f, 0.f, 0.f};

  // hoisted per-thread staging bases (branch-free: halo pre-zeroed)
  const char* abase = (const char*)Apack + (size_t)ot * BM * 64 + lane * 16;
  const char* bbase = (const char*)xb +
      (pad_px(n, h, 0) + (lane >> 2)) * (size_t)(CS * 2) + (lane & 3) * 16;

  auto mfma_cluster = [&](const f16x8* af, const f16x8* bfr) {
    __builtin_amdgcn_s_setprio(1);
#pragma unroll
    for (int mi = 0; mi < MF; mi++)
#pragma unroll
      for (int ni = 0; ni < NF; ni++)
        acc[mi][ni] = __builtin_amdgcn_mfma_f32_16x16x32_f16(af[mi], bfr[ni], acc[mi][ni], 0, 0, 0);
    __builtin_amdgcn_s_setprio(0);
  };

  if constexpr (!HEAD) {
    // per triple jj = kt*CC + c: stage A(3 sub-kk, 18KB) + B row window (15KB),
    // then 3x21 MFMA reading the shared B row at +/-1 px offsets.
    auto stage_triple = [&](char* base, int jj) {
      const int kt = jj / CC, c = jj % CC;
      const char* asrcj = abase + (size_t)(jj * 3) * (OT * 64);
      const char* bsrcj = bbase + ((ptrdiff_t)(kt - 1) * WP - 1) * (CS * 2) + c * 64;
#pragma unroll
      for (int i = 0; i < (TCHT + NWV - 1) / NWV; i++) {
        int ck = wv + i * NWV;
        if (ck < TCHT) {
          char* dst = base + ck * 1024;      // wave-uniform
          const char* src;
          if (ck < ACHT) {
            int d = (ck >= 2 * A1) ? 2 : ((ck >= A1) ? 1 : 0);
            src = asrcj + (size_t)d * (OT * 64) + (size_t)(ck - d * A1) * 1024;
          } else {
            src = bsrcj + (size_t)(ck - ACHT) * (16 * CS * 2);
          }
          gload16(src, dst);
        }
      }
    };
    auto compute_d = [&](const char* base, int d) {
      const char* Ab = base + d * (BM * 64);
      const char* Bb = base + ACHT * 1024;
      f16x8 af[MF], bfr[NF];
#pragma unroll
      for (int mi = 0; mi < MF; mi++)
        af[mi] = *(const f16x8*)(Ab + (obase + mi * 16) * 64 + aoff);
#pragma unroll
      for (int ni = 0; ni < NF; ni++) {
        int wp = wnbase + ni * 16 + l15 + d - 1;     // global tap pixel in row
        int sw = ((lhi ^ (wp >> 1)) & 3) << 4;
        bfr[ni] = *(const f16x8*)(Bb + (wp + 1) * 64 + sw);
      }
      mfma_cluster(af, bfr);
    };
    char* b0 = lds;
    char* b1 = lds + TCHT * 1024;
    stage_triple(b0, 0);
    for (int jj = 0; jj < NTR; ++jj) {
      if (jj + 1 < NTR) {
        stage_triple((jj & 1) ? b0 : b1, jj + 1);
        if (wv == 0) { WAITVM(9); } else { WAITVM(8); }   // own stage(jj) retired
      } else {
        WAITVM(0);
      }
      barrier_sync();
      const char* b = (jj & 1) ? b1 : b0;
      compute_d(b, 0);
      compute_d(b, 1);
      compute_d(b, 2);
      barrier_sync();
    }
  } else {
    // ---- block-shared double buffer + __syncthreads (proven); q' decode ----
    constexpr int HTCH = 1 + 14;            // A 1KB + B 14KB per buffer
    auto stage_blk = [&](char* base, int t) {
      const int d = t % 3, u = t / 3;
      const int c = u % CC, kt = u / CC;
      const int doff = (kt - 1) * WP + (d - 1);
      const char* asrc = abase + (size_t)t * (OT * 64);
      const char* bsrc = bbase + (ptrdiff_t)doff * (CS * 2) + c * 64;
      for (int ck = wv; ck < HTCH; ck += NWV) {
        char* dst = base + ck * 1024;
        if (ck < 1) gload16(asrc, dst);
        else        gload16(bsrc + (size_t)(ck - 1) * (16 * CS * 2), dst);
      }
    };
    auto read_frags_blk = [&](const char* base, int t, f16x8* af, f16x8* bfr) {
      const int dw = (t % 3) - 1;
      af[0] = *(const f16x8*)(base + aoff);          // aoff already includes l15*64
#pragma unroll
      for (int ni = 0; ni < NF; ni++) {
        int px = wnbase + ni * 16 + l15;
        int sw = ((lhi ^ ((px + dw) >> 1)) & 3) << 4;
        bfr[ni] = *(const f16x8*)(base + 1024 + px * 64 + sw);
      }
    };
    f16x8 af[MF], bfr[NF];
    stage_blk(lds, 0);
    __syncthreads();
    int buf = 0;
    for (int t = 0; t < NCH; ++t) {
      if (t + 1 < NCH) stage_blk(lds + (buf ^ 1) * 15360, t + 1);
      read_frags_blk(lds + buf * 15360, t, af, bfr);
      mfma_cluster(af, bfr);
      __syncthreads();
      buf ^= 1;
    }
  }

  const size_t prow = pad_px(n, h, 0);
  if constexpr (!HEAD) {
    // store fp16 padded-NHWC output
#pragma unroll
    for (int mi = 0; mi < MF; mi++) {
#pragma unroll
      for (int ni = 0; ni < NF; ni++) {
        int o = obase + mi * 16 + lhi * 4;
        int w = wnbase + ni * 16 + l15;
        f16x4 v4;
#pragma unroll
        for (int j = 0; j < 4; j++) v4[j] = (f16)acc[mi][ni][j];
        *(f16x4*)(y + (prow + w) * OT + ot * BM + o) = v4;
      }
    }
    // fused BN stats: per-channel sum / sumsq partials
    float sv[MF][4], qv[MF][4];
#pragma unroll
    for (int mi = 0; mi < MF; mi++)
#pragma unroll
      for (int j = 0; j < 4; j++) {
        float s = 0.f, q = 0.f;
#pragma unroll
        for (int ni = 0; ni < NF; ni++) {
          float v = acc[mi][ni][j];
          s += v; q += v * v;
        }
        sv[mi][j] = s; qv[mi][j] = q;
      }
#pragma unroll
    for (int m = 1; m < 16; m <<= 1) {
#pragma unroll
      for (int mi = 0; mi < MF; mi++)
#pragma unroll
        for (int j = 0; j < 4; j++) {
          sv[mi][j] += __shfl_xor(sv[mi][j], m);
          qv[mi][j] += __shfl_xor(qv[mi][j], m);
        }
    }
    if (l15 == 0) {
#pragma unroll
      for (int mi = 0; mi < MF; mi++)
#pragma unroll
        for (int j = 0; j < 4; j++) {
          int ch = ot * BM + obase + mi * 16 + lhi * 4 + j;
          atomicAdd(&sums[ch], sv[mi][j]);
          atomicAdd(&sumsq[ch], qv[mi][j]);
        }
    }
  } else {
    if (lhi == 0) {
      float b0 = bcp[0], b1 = bgp[0], b2 = bgp[1];
#pragma unroll
      for (int ni = 0; ni < NF; ni++) {
        int w = wnbase + ni * 16 + l15;
        float c0 = acc[0][ni][0] + b0;
        c0 = 1.f / (1.f + expf(-c0));
        float c1 = acc[0][ni][1] + b1;
        float c2 = acc[0][ni][2] + b2;
        outh[((size_t)(n * 3 + 0) * H_IMG + h) * W_IMG + w] = c0;
        outh[((size_t)(n * 3 + 1) * H_IMG + h) * W_IMG + w] = c1;
        outh[((size_t)(n * 3 + 2) * H_IMG + h) * W_IMG + w] = c2;
      }
    }
  }
}

// ---------------- BN coefficient recompute (fused into consumers) ---------------
template<int O>
__device__ __forceinline__ void bn_coef(const float* __restrict__ sums,
                                        const float* __restrict__ sumsq,
                                        const float* __restrict__ g,
                                        const float* __restrict__ b,
                                        float* sc, float* sh, int tid, int nt) {
  const float inv = 1.0f / (float)P_TOT;
  for (int t = tid; t < O; t += nt) {
    float mean = sums[t] * inv;
    float var  = fmaxf(sumsq[t] * inv - mean * mean, 0.f);
    int gi = (t < O / 2) ? t : (t - O / 2);
    float s = g[gi] * rsqrtf(var + 1e-5f);
    sc[t] = s;
    sh[t] = b[gi] - mean * s;
  }
}

// ------- in-place BN + ReLU + chunk-swizzle, with fused halo-zero blocks --------
template<int O>
__global__ void k_packip(f16* __restrict__ y,
                         const float* __restrict__ sums, const float* __restrict__ sumsq,
                         const float* __restrict__ g, const float* __restrict__ b) {
  constexpr int G32 = O / 32;
  constexpr int MAIN = P_TOT * G32 / 256;
  if (blockIdx.x >= MAIN) {
    halo_zero(y, O, (blockIdx.x - MAIN) * 256 + threadIdx.x);
    return;
  }
  __shared__ float sc[O], sh[O];
  bn_coef<O>(sums, sumsq, g, b, sc, sh, threadIdx.x, 256);
  __syncthreads();
  int gid = blockIdx.x * 256 + threadIdx.x;
  int gg = gid % G32;
  int p = gid / G32;
  int w = p % W_IMG;
  int hh = (p / W_IMG) % H_IMG;
  int nn = p / (W_IMG * H_IMG);
  f16* base = y + pad_px(nn, hh, w) * O + gg * 32;
  f16x8 in[4];
#pragma unroll
  for (int ch = 0; ch < 4; ch++) in[ch] = *(const f16x8*)(base + ch * 8);
  int sw = (w >> 1) & 3;
  f16x8 outv[4];
#pragma unroll
  for (int ch = 0; ch < 4; ch++) {
#pragma unroll
    for (int j = 0; j < 8; j++) {
      int cdx = gg * 32 + ch * 8 + j;
      float f = fmaxf(fmaf((float)in[ch][j], sc[cdx], sh[cdx]), 0.f);
      outv[ch][j] = (f16)f;
    }
  }
#pragma unroll
  for (int ch = 0; ch < 4; ch++) *(f16x8*)(base + ((ch ^ sw) & 3) * 8) = outv[ch];
}

// --- BN(L4) + ReLU + complex magnitude -> 96ch swizzled, + fused halo96(out) ----
__global__ void k_mag(const f16* __restrict__ y,
                      const float* __restrict__ sums, const float* __restrict__ sumsq,
                      const float* __restrict__ g, const float* __restrict__ b,
                      f16* __restrict__ mg) {
  constexpr int MAIN = P_TOT * 12 / 256;
  if (blockIdx.x >= MAIN) {
    halo_zero(mg, 96, (blockIdx.x - MAIN) * 256 + threadIdx.x);
    return;
  }
  __shared__ float sc[192], sh[192];
  bn_coef<192>(sums, sumsq, g, b, sc, sh, threadIdx.x, 256);
  __syncthreads();
  int gid = blockIdx.x * 256 + threadIdx.x;
  int c8 = gid % 12;
  int p  = gid / 12;
  int w  = p % W_IMG;
  int hh = (p / W_IMG) % H_IMG;
  int nn = p / (W_IMG * H_IMG);
  size_t pp = pad_px(nn, hh, w);
  f16x8 r8 = *(const f16x8*)(y + pp * 192 + c8 * 8);
  f16x8 i8 = *(const f16x8*)(y + pp * 192 + 96 + c8 * 8);
  f16x8 outv;
#pragma unroll
  for (int j = 0; j < 8; j++) {
    int cdx = c8 * 8 + j;
    float rr = fmaxf(fmaf((float)r8[j], sc[cdx], sh[cdx]), 0.f);
    float ii = fmaxf(fmaf((float)i8[j], sc[96 + cdx], sh[96 + cdx]), 0.f);
    outv[j] = (f16)sqrtf(rr * rr + ii * ii);
  }
  int c8s = (c8 & ~3) | ((c8 ^ (w >> 1)) & 3);
  *(f16x8*)(mg + pp * 96 + c8s * 8) = outv;
}

// ------------------------------------------------------------------------------
extern "C" void kernel_launch(void* const* d_in, const int* in_sizes, int n_in,
                              void* d_out, int out_size, void* d_ws, size_t ws_size,
                              hipStream_t stream) {
  const float* x   = (const float*)d_in[0];
  const float* w1r = (const float*)d_in[1];
  const float* w1i = (const float*)d_in[2];
  const float* g1  = (const float*)d_in[3];
  const float* b1  = (const float*)d_in[4];
  const float* w2r = (const float*)d_in[5];
  const float* w2i = (const float*)d_in[6];
  const float* g2  = (const float*)d_in[7];
  const float* b2  = (const float*)d_in[8];
  const float* w3r = (const float*)d_in[9];
  const float* w3i = (const float*)d_in[10];
  const float* g3  = (const float*)d_in[11];
  const float* b3  = (const float*)d_in[12];
  const float* w4r = (const float*)d_in[13];
  const float* w4i = (const float*)d_in[14];
  const float* g4  = (const float*)d_in[15];
  const float* b4  = (const float*)d_in[16];
  const float* wc  = (const float*)d_in[17];
  const float* bcp = (const float*)d_in[18];
  const float* wg  = (const float*)d_in[19];
  const float* bgp = (const float*)d_in[20];
  float* out = (float*)d_out;

  char* ws = (char*)d_ws;
  if (ws_size < 137500000ULL) return;

  auto S  = [&](int L) { return (float*)(ws + 16384 + L * 4096); };
  auto Q  = [&](int L) { return (float*)(ws + 16384 + L * 4096) + 512; };
  f16* A1 = (f16*)(ws + 65536);
  f16* A2 = (f16*)(ws + 1392640);
  f16* A3 = (f16*)(ws + 2387968);
  f16* A4 = (f16*)(ws + 3051520);
  f16* AH = (f16*)(ws + 3715072);
  f16* SLA = (f16*)(ws + 4194304);     // padded slab A
  f16* SLB = (f16*)(ws + 65011712);    // padded slab B

  hipMemsetAsync(d_ws, 0, 49152, stream);  // stats sums

  // pack input (+SLA/256 halo); all weight packs in one launch
  k_pack_x<<<P_TOT / 32 + 484, 256, 0, stream>>>(x, SLA);
  k_pack_w_all<<<(1838592) / 256, 256, 0, stream>>>(w1r, w1i, w2r, w2i, w3r, w3i,
                                                    w4r, w4i, wc, wg, A1, A2, A3, A4, AH);

  // L1: 256 -> 288  (read SLA/256, write SLB/288); packip fuses SLB/288 halo
  k_gemm<96, 288, 256, 2, 2, false><<<1536, 256, 0, stream>>>(SLA, A1, SLB, nullptr, nullptr, nullptr, S(0), Q(0));
  k_packip<288><<<P_TOT * 9 / 256 + 545, 256, 0, stream>>>(SLB, S(0), Q(0), g1, b1);

  // L2: 288 -> 192  (read SLB/288, write SLA/192); packip fuses SLA/192 halo
  k_gemm<96, 192, 288, 2, 2, false><<<1024, 256, 0, stream>>>(SLB, A2, SLA, nullptr, nullptr, nullptr, S(1), Q(1));
  k_packip<192><<<P_TOT * 6 / 256 + 363, 256, 0, stream>>>(SLA, S(1), Q(1), g2, b2);

  // L3: 192 -> 192  (read SLA/192, write SLB/192); packip fuses SLB/192 halo
  k_gemm<96, 192, 192, 2, 2, false><<<1024, 256, 0, stream>>>(SLA, A3, SLB, nullptr, nullptr, nullptr, S(2), Q(2));
  k_packip<192><<<P_TOT * 6 / 256 + 363, 256, 0, stream>>>(SLB, S(2), Q(2), g3, b3);

  // L4: 192 -> 192  (read SLB/192, write SLA/192)
  k_gemm<96, 192, 192, 2, 2, false><<<1024, 256, 0, stream>>>(SLB, A4, SLA, nullptr, nullptr, nullptr, S(3), Q(3));

  // BN+ReLU+magnitude -> 96ch head input (read SLA/192, write SLB/96) + SLB/96 halo
  k_mag<<<P_TOT * 12 / 256 + 182, 256, 0, stream>>>(SLA, S(3), Q(3), g4, b4, SLB);

  // head: 96 -> 3 (sigmoid on ch0), writes NCHW fp32 output
  k_gemm<16, 16, 96, 1, 2, true><<<512, 128, 0, stream>>>(SLB, AH, nullptr, out, bcp, bgp, nullptr, nullptr);

  (void)in_sizes; (void)n_in; (void)out_size;
}